// Round 1
// baseline (517.529 us; speedup 1.0000x reference)
//
#include <hip/hip_runtime.h>

#define N_NODES 50000
#define N_EDGES 800000
#define N_FEAT  128
#define N_HID   64

// hw[row][col] = sum_k x[row*K+k] * w[k*64+col]
// row = tid>>6 is wave-uniform -> x loads are scalar broadcasts; w fits L1.
template <int K>
__global__ void gemm_rowcol(const float* __restrict__ a, const float* __restrict__ w,
                            float* __restrict__ o) {
    int t = blockIdx.x * blockDim.x + threadIdx.x;
    int row = t >> 6;
    int col = t & 63;
    if (row >= N_NODES) return;
    const float* ar = a + (long)row * K;
    float acc = 0.f;
#pragma unroll 8
    for (int k = 0; k < K; ++k)
        acc = fmaf(ar[k], w[k * N_HID + col], acc);
    o[(long)row * N_HID + col] = acc;
}

// wave-per-edge: lane f handles feature f
__global__ void scatter_edges(const float* __restrict__ hw, const int* __restrict__ src,
                              const int* __restrict__ dst, const float* __restrict__ ew,
                              float* __restrict__ agg) {
    int t = blockIdx.x * blockDim.x + threadIdx.x;
    int e = t >> 6;
    int f = t & 63;
    if (e >= N_EDGES) return;
    int s = src[e];
    int d = dst[e];
    float w = ew[e];
    float v = hw[(long)s * N_HID + f] * w;
    atomicAdd(&agg[(long)d * N_HID + f], v);
}

// h = relu(agg + b); agg = 0 (ready for layer 2)
__global__ void relu_bias_clear(float* __restrict__ agg, const float* __restrict__ b,
                                float* __restrict__ h) {
    int i = blockIdx.x * blockDim.x + threadIdx.x;
    if (i >= N_NODES * N_HID) return;
    float v = agg[i] + b[i & 63];
    h[i] = v > 0.f ? v : 0.f;
    agg[i] = 0.f;
}

__global__ void add_bias(const float* __restrict__ agg, const float* __restrict__ b,
                         float* __restrict__ o) {
    int i = blockIdx.x * blockDim.x + threadIdx.x;
    if (i >= N_NODES * N_HID) return;
    o[i] = agg[i] + b[i & 63];
}

extern "C" void kernel_launch(void* const* d_in, const int* in_sizes, int n_in,
                              void* d_out, int out_size, void* d_ws, size_t ws_size,
                              hipStream_t stream) {
    const float* x  = (const float*)d_in[0];
    const int*   ei = (const int*)d_in[1];   // [2, E] flat: src then dst
    const float* ew = (const float*)d_in[2];
    const float* w1 = (const float*)d_in[3];
    const float* b1 = (const float*)d_in[4];
    const float* w2 = (const float*)d_in[5];
    const float* b2 = (const float*)d_in[6];
    float* out = (float*)d_out;

    float* hw  = (float*)d_ws;                       // [N_NODES, 64]
    float* agg = hw + (size_t)N_NODES * N_HID;       // [N_NODES, 64]

    const int* src = ei;
    const int* dst = ei + N_EDGES;

    const int NV = N_NODES * N_HID;                  // 3.2M
    dim3 blk(256);
    dim3 gemm_grid((NV + 255) / 256);
    dim3 scat_grid(((size_t)N_EDGES * 64 + 255) / 256);

    hipMemsetAsync(agg, 0, (size_t)NV * sizeof(float), stream);

    // Layer 1
    gemm_rowcol<N_FEAT><<<gemm_grid, blk, 0, stream>>>(x, w1, hw);
    scatter_edges<<<scat_grid, blk, 0, stream>>>(hw, src, dst, ew, agg);
    relu_bias_clear<<<gemm_grid, blk, 0, stream>>>(agg, b1, hw);  // h -> hw, agg -> 0

    // Layer 2 (hw2 staged in d_out, then aggregated into agg, then bias -> out)
    gemm_rowcol<N_HID><<<gemm_grid, blk, 0, stream>>>(hw, w2, out);
    scatter_edges<<<scat_grid, blk, 0, stream>>>(out, src, dst, ew, agg);
    add_bias<<<gemm_grid, blk, 0, stream>>>(agg, b2, out);
}

// Round 2
// 394.966 us; speedup vs baseline: 1.3103x; 1.3103x over previous
//
#include <hip/hip_runtime.h>

#define N_NODES 50000
#define N_EDGES 800000
#define N_FEAT  128
#define N_HID   64
#define SCAN_B  512

// ---------- GEMM: o[row][col] = sum_k a[row*K+k] * w[k*64+col] ----------
template <int K>
__global__ void gemm_rowcol(const float* __restrict__ a, const float* __restrict__ w,
                            float* __restrict__ o) {
    int t = blockIdx.x * blockDim.x + threadIdx.x;
    int row = t >> 6;
    int col = t & 63;
    if (row >= N_NODES) return;
    const float* ar = a + (long)row * K;
    float acc = 0.f;
#pragma unroll 8
    for (int k = 0; k < K; ++k)
        acc = fmaf(ar[k], w[k * N_HID + col], acc);
    o[(long)row * N_HID + col] = acc;
}

// ---------- CSR build: counting sort by dst ----------
__global__ void hist_dst(const int* __restrict__ dst, int* __restrict__ cnt) {
    int e = blockIdx.x * blockDim.x + threadIdx.x;
    if (e < N_EDGES) atomicAdd(&cnt[dst[e]], 1);
}

// per-block exclusive scan; block sums out
__global__ void scan_block(const int* __restrict__ cnt, int* __restrict__ exc,
                           int* __restrict__ bsum) {
    __shared__ int lds[SCAN_B];
    int tid = threadIdx.x;
    int i = blockIdx.x * SCAN_B + tid;
    int v = (i < N_NODES) ? cnt[i] : 0;
    lds[tid] = v;
    __syncthreads();
    for (int off = 1; off < SCAN_B; off <<= 1) {
        int t = (tid >= off) ? lds[tid - off] : 0;
        __syncthreads();
        lds[tid] += t;
        __syncthreads();
    }
    if (i < N_NODES) exc[i] = lds[tid] - v;            // exclusive within block
    if (tid == SCAN_B - 1) bsum[blockIdx.x] = lds[tid]; // block total
}

// single block: exclusive scan of block sums (nb <= 128)
__global__ void scan_bsum(int* __restrict__ bsum, int nb) {
    __shared__ int lds[128];
    int tid = threadIdx.x;
    int v = (tid < nb) ? bsum[tid] : 0;
    lds[tid] = v;
    __syncthreads();
    for (int off = 1; off < 128; off <<= 1) {
        int t = (tid >= off) ? lds[tid - off] : 0;
        __syncthreads();
        lds[tid] += t;
        __syncthreads();
    }
    if (tid < nb) bsum[tid] = lds[tid] - v;            // exclusive
}

__global__ void scan_finalize(int* __restrict__ start, int* __restrict__ cursor,
                              const int* __restrict__ bsum) {
    int i = blockIdx.x * blockDim.x + threadIdx.x;
    if (i < N_NODES) {
        int s = start[i] + bsum[i / SCAN_B];
        start[i] = s;
        cursor[i] = s;
    }
    if (i == 0) start[N_NODES] = N_EDGES;
}

// place packed edge records sorted by dst
__global__ void fill_edges(const int* __restrict__ src, const int* __restrict__ dst,
                           const float* __restrict__ ew, int* __restrict__ cursor,
                           int2* __restrict__ edges) {
    int e = blockIdx.x * blockDim.x + threadIdx.x;
    if (e >= N_EDGES) return;
    int d = dst[e];
    int p = atomicAdd(&cursor[d], 1);
    edges[p] = make_int2(src[e], __float_as_int(ew[e]));
}

// ---------- pull aggregation: o[n][f] = relu?(sum_e hw[src_e][f]*w_e + b[f]) ----------
template <bool RELU>
__global__ void gcn_agg(const float* __restrict__ hw, const int2* __restrict__ edges,
                        const int* __restrict__ start, const float* __restrict__ b,
                        float* __restrict__ o) {
    int t = blockIdx.x * blockDim.x + threadIdx.x;
    int n = t >> 6;
    int f = t & 63;
    if (n >= N_NODES) return;
    int i0 = start[n], i1 = start[n + 1];
    float acc = 0.f;
    for (int i = i0; i < i1; ++i) {
        int2 ed = edges[i];                       // wave-uniform 8B load
        acc = fmaf(hw[(long)ed.x * N_HID + f], __int_as_float(ed.y), acc);
    }
    acc += b[f];
    if (RELU) acc = fmaxf(acc, 0.f);
    o[(long)n * N_HID + f] = acc;
}

extern "C" void kernel_launch(void* const* d_in, const int* in_sizes, int n_in,
                              void* d_out, int out_size, void* d_ws, size_t ws_size,
                              hipStream_t stream) {
    const float* x  = (const float*)d_in[0];
    const int*   ei = (const int*)d_in[1];   // [2, E] flat: src then dst
    const float* ew = (const float*)d_in[2];
    const float* w1 = (const float*)d_in[3];
    const float* b1 = (const float*)d_in[4];
    const float* w2 = (const float*)d_in[5];
    const float* b2 = (const float*)d_in[6];
    float* out = (float*)d_out;

    const int* src = ei;
    const int* dst = ei + N_EDGES;

    // workspace layout
    float* hw    = (float*)d_ws;                          // 3.2M floats (12.8 MB)
    int2*  edges = (int2*)(hw + (size_t)N_NODES * N_HID); // 800k int2 (6.4 MB), 8B-aligned
    int*   cnt    = (int*)(edges + N_EDGES);              // 50000
    int*   start  = cnt + N_NODES;                        // 50001 (+pad)
    int*   cursor = start + N_NODES + 8;                  // 50000
    int*   bsum   = cursor + N_NODES;                     // <=128

    const int NB = (N_NODES + SCAN_B - 1) / SCAN_B;       // 98
    dim3 blk(256);
    dim3 egrid((N_EDGES + 255) / 256);                    // 3125
    dim3 ngrid((N_NODES * N_HID + 255) / 256);            // 12500
    dim3 sgrid((N_NODES + 255) / 256);                    // 196

    // ---- build CSR (once, shared by both layers) ----
    hipMemsetAsync(cnt, 0, (size_t)N_NODES * sizeof(int), stream);
    hist_dst<<<egrid, blk, 0, stream>>>(dst, cnt);
    scan_block<<<NB, SCAN_B, 0, stream>>>(cnt, start, bsum);
    scan_bsum<<<1, 128, 0, stream>>>(bsum, NB);
    scan_finalize<<<sgrid, blk, 0, stream>>>(start, cursor, bsum);
    fill_edges<<<egrid, blk, 0, stream>>>(src, dst, ew, cursor, edges);

    // ---- layer 1: hw = x@w1; h = relu(agg + b1) -> staged in d_out ----
    gemm_rowcol<N_FEAT><<<ngrid, blk, 0, stream>>>(x, w1, hw);
    gcn_agg<true><<<ngrid, blk, 0, stream>>>(hw, edges, start, b1, out);

    // ---- layer 2: hw = h@w2; out = agg + b2 ----
    gemm_rowcol<N_HID><<<ngrid, blk, 0, stream>>>(out, w2, hw);
    gcn_agg<false><<<ngrid, blk, 0, stream>>>(hw, edges, start, b2, out);
}

// Round 3
// 210.709 us; speedup vs baseline: 2.4561x; 1.8745x over previous
//
#include <hip/hip_runtime.h>

#define N_NODES 50000
#define N_EDGES 800000
#define N_FEAT  128
#define N_HID   64
#define SCAN_B  512

__device__ inline void fma4(float4& acc, float s, const float4& w) {
    acc.x = fmaf(s, w.x, acc.x);
    acc.y = fmaf(s, w.y, acc.y);
    acc.z = fmaf(s, w.z, acc.z);
    acc.w = fmaf(s, w.w, acc.w);
}

// ---------- tiled GEMM: o[row][col] = sum_k a[row*K+k] * w[k*64+col] ----------
// block = 256 threads computes 32 rows x 64 cols; w staged in LDS.
// thread: rows (row0, row0+1), cols c4..c4+3  -> 8 accumulators.
template <int K>
__global__ __launch_bounds__(256) void gemm_tile(const float* __restrict__ a,
                                                 const float* __restrict__ w,
                                                 float* __restrict__ o) {
    __shared__ float lw[K * N_HID];
    int tid = threadIdx.x;
    for (int idx = tid * 4; idx < K * N_HID; idx += 256 * 4)
        *(float4*)&lw[idx] = *(const float4*)&w[idx];
    __syncthreads();

    int row0 = blockIdx.x * 32 + (tid >> 4) * 2;
    if (row0 >= N_NODES) return;
    bool two = (row0 + 1) < N_NODES;
    int c4 = (tid & 15) * 4;

    const float* a0 = a + (long)row0 * K;
    const float* a1 = two ? (a0 + K) : a0;

    float4 acc0 = make_float4(0.f, 0.f, 0.f, 0.f);
    float4 acc1 = acc0;

#pragma unroll 8
    for (int k4 = 0; k4 < K / 4; ++k4) {
        float4 xa = *(const float4*)(a0 + k4 * 4);
        float4 xb = *(const float4*)(a1 + k4 * 4);
        const float* wk = &lw[(k4 * 4) * N_HID + c4];
        float4 w0 = *(const float4*)(wk);
        float4 w1 = *(const float4*)(wk + N_HID);
        float4 w2 = *(const float4*)(wk + 2 * N_HID);
        float4 w3 = *(const float4*)(wk + 3 * N_HID);
        fma4(acc0, xa.x, w0); fma4(acc1, xb.x, w0);
        fma4(acc0, xa.y, w1); fma4(acc1, xb.y, w1);
        fma4(acc0, xa.z, w2); fma4(acc1, xb.z, w2);
        fma4(acc0, xa.w, w3); fma4(acc1, xb.w, w3);
    }

    float* op = o + (long)row0 * N_HID + c4;
    *(float4*)op = acc0;
    if (two) *(float4*)(op + N_HID) = acc1;
}

// ---------- CSR build: counting sort by dst ----------
__global__ void hist_dst(const int* __restrict__ dst, int* __restrict__ cnt) {
    int e = blockIdx.x * blockDim.x + threadIdx.x;
    if (e < N_EDGES) atomicAdd(&cnt[dst[e]], 1);
}

__global__ void scan_block(const int* __restrict__ cnt, int* __restrict__ exc,
                           int* __restrict__ bsum) {
    __shared__ int lds[SCAN_B];
    int tid = threadIdx.x;
    int i = blockIdx.x * SCAN_B + tid;
    int v = (i < N_NODES) ? cnt[i] : 0;
    lds[tid] = v;
    __syncthreads();
    for (int off = 1; off < SCAN_B; off <<= 1) {
        int t = (tid >= off) ? lds[tid - off] : 0;
        __syncthreads();
        lds[tid] += t;
        __syncthreads();
    }
    if (i < N_NODES) exc[i] = lds[tid] - v;
    if (tid == SCAN_B - 1) bsum[blockIdx.x] = lds[tid];
}

__global__ void scan_bsum(int* __restrict__ bsum, int nb) {
    __shared__ int lds[128];
    int tid = threadIdx.x;
    int v = (tid < nb) ? bsum[tid] : 0;
    lds[tid] = v;
    __syncthreads();
    for (int off = 1; off < 128; off <<= 1) {
        int t = (tid >= off) ? lds[tid - off] : 0;
        __syncthreads();
        lds[tid] += t;
        __syncthreads();
    }
    if (tid < nb) bsum[tid] = lds[tid] - v;
}

__global__ void scan_finalize(int* __restrict__ start, int* __restrict__ cursor,
                              const int* __restrict__ bsum) {
    int i = blockIdx.x * blockDim.x + threadIdx.x;
    if (i < N_NODES) {
        int s = start[i] + bsum[i / SCAN_B];
        start[i] = s;
        cursor[i] = s;
    }
    if (i == 0) start[N_NODES] = N_EDGES;
}

__global__ void fill_edges(const int* __restrict__ src, const int* __restrict__ dst,
                           const float* __restrict__ ew, int* __restrict__ cursor,
                           int2* __restrict__ edges) {
    int e = blockIdx.x * blockDim.x + threadIdx.x;
    if (e >= N_EDGES) return;
    int d = dst[e];
    int p = atomicAdd(&cursor[d], 1);
    edges[p] = make_int2(src[e], __float_as_int(ew[e]));
}

// ---------- pull aggregation, unroll-4 for latency overlap ----------
template <bool RELU>
__global__ void gcn_agg(const float* __restrict__ hw, const int2* __restrict__ edges,
                        const int* __restrict__ start, const float* __restrict__ b,
                        float* __restrict__ o) {
    int t = blockIdx.x * blockDim.x + threadIdx.x;
    int n = t >> 6;
    int f = t & 63;
    if (n >= N_NODES) return;
    int i0 = start[n], i1 = start[n + 1];
    float bias = b[f];
    float acc = 0.f;
    int i = i0;
    for (; i + 4 <= i1; i += 4) {
        int2 e0 = edges[i];
        int2 e1 = edges[i + 1];
        int2 e2 = edges[i + 2];
        int2 e3 = edges[i + 3];
        float v0 = hw[(long)e0.x * N_HID + f];
        float v1 = hw[(long)e1.x * N_HID + f];
        float v2 = hw[(long)e2.x * N_HID + f];
        float v3 = hw[(long)e3.x * N_HID + f];
        acc = fmaf(v0, __int_as_float(e0.y), acc);
        acc = fmaf(v1, __int_as_float(e1.y), acc);
        acc = fmaf(v2, __int_as_float(e2.y), acc);
        acc = fmaf(v3, __int_as_float(e3.y), acc);
    }
    for (; i < i1; ++i) {
        int2 ed = edges[i];
        acc = fmaf(hw[(long)ed.x * N_HID + f], __int_as_float(ed.y), acc);
    }
    acc += bias;
    if (RELU) acc = fmaxf(acc, 0.f);
    o[(long)n * N_HID + f] = acc;
}

extern "C" void kernel_launch(void* const* d_in, const int* in_sizes, int n_in,
                              void* d_out, int out_size, void* d_ws, size_t ws_size,
                              hipStream_t stream) {
    const float* x  = (const float*)d_in[0];
    const int*   ei = (const int*)d_in[1];   // [2, E] flat: src then dst
    const float* ew = (const float*)d_in[2];
    const float* w1 = (const float*)d_in[3];
    const float* b1 = (const float*)d_in[4];
    const float* w2 = (const float*)d_in[5];
    const float* b2 = (const float*)d_in[6];
    float* out = (float*)d_out;

    const int* src = ei;
    const int* dst = ei + N_EDGES;

    float* hw    = (float*)d_ws;                          // 3.2M floats (12.8 MB)
    int2*  edges = (int2*)(hw + (size_t)N_NODES * N_HID); // 800k int2 (6.4 MB)
    int*   cnt    = (int*)(edges + N_EDGES);
    int*   start  = cnt + N_NODES;
    int*   cursor = start + N_NODES + 8;
    int*   bsum   = cursor + N_NODES;

    const int NB = (N_NODES + SCAN_B - 1) / SCAN_B;
    dim3 blk(256);
    dim3 egrid((N_EDGES + 255) / 256);
    dim3 ngrid((N_NODES * N_HID + 255) / 256);
    dim3 sgrid((N_NODES + 255) / 256);
    dim3 ggrid((N_NODES + 31) / 32);                      // 1563

    // ---- build CSR ----
    hipMemsetAsync(cnt, 0, (size_t)N_NODES * sizeof(int), stream);
    hist_dst<<<egrid, blk, 0, stream>>>(dst, cnt);
    scan_block<<<NB, SCAN_B, 0, stream>>>(cnt, start, bsum);
    scan_bsum<<<1, 128, 0, stream>>>(bsum, NB);
    scan_finalize<<<sgrid, blk, 0, stream>>>(start, cursor, bsum);
    fill_edges<<<egrid, blk, 0, stream>>>(src, dst, ew, cursor, edges);

    // ---- layer 1 ----
    gemm_tile<N_FEAT><<<ggrid, blk, 0, stream>>>(x, w1, hw);
    gcn_agg<true><<<ngrid, blk, 0, stream>>>(hw, edges, start, b1, out);

    // ---- layer 2 ----
    gemm_tile<N_HID><<<ggrid, blk, 0, stream>>>(out, w2, hw);
    gcn_agg<false><<<ngrid, blk, 0, stream>>>(hw, edges, start, b2, out);
}